// Round 4
// baseline (315.982 us; speedup 1.0000x reference)
//
#include <hip/hip_runtime.h>
#include <math.h>

#define NB    16        // batch
#define NC    25        // channels
#define HW    65536     // 256*256
#define CHW   (NC * HW)
#define EPSF  1e-8f
#define TPB   128       // 2 waves -- small blocks so 8 fit per CU
#define BPI   128       // blocks per image; slab = 512 px
#define SLAB  512
#define GR    5         // channels per staged group
#define NGRP  5         // 25 channels = 5 groups
#define NBLK  (NB * BPI) // 2048 blocks

union F4 { float4 v; float a[4]; };

typedef const float __attribute__((address_space(1)))* gp_t;  // global
typedef float       __attribute__((address_space(3)))* lp_t;  // LDS

__device__ __forceinline__ float wave_reduce(float v) {
#pragma unroll
    for (int o = 32; o > 0; o >>= 1) v += __shfl_down(v, o, 64);
    return v;
}

// R11: R7's global_load_lds staging, but 8 blocks/CU instead of 1.
// History: R7 (80KB LDS, 1 block/CU) = 75us; every attempt to pipeline
// WITHIN a block failed structurally: __syncthreads drains vmcnt(0)
// including prefetches (R8), the scheduler sinks register pipelines (R9,
// VGPR=76), regalloc spills them when fenced (R10, WRITE_SIZE 19.5MB of
// scratch). Conclusion: intra-block MLP is unobtainable at HIP level here.
// Fix: INTER-block MLP. Drop the (useless) double buffer, shrink to
// TPB=128/SLAB=512 -> LDS = 10*512*4 = 20480B exactly -> 8 blocks/CU
// (163840/20480=8), 2048-block grid = 8/CU resident. Each block is serial
// {stage 20KB -> drain -> consume}, but 8 staggered blocks keep the CU's
// memory pipe continuously fed (~40-100KB in flight vs ~22KB needed).
// Reduction scratch is aliased into the LDS buffer (after final sync) so
// the block stays exactly at the 20480B granule.
__global__ __launch_bounds__(TPB) void yolo_main(const float* __restrict__ outputs,
                                                 const float* __restrict__ labels,
                                                 float* __restrict__ acc,
                                                 unsigned* __restrict__ ticket,
                                                 float* __restrict__ out) {
    __shared__ float lds[2 * GR][SLAB];      // 20480 B, single buffer

    const int b    = blockIdx.x / BPI;
    const int slab = blockIdx.x % BPI;
    const size_t base = (size_t)b * CHW + (size_t)slab * SLAB;
    const int wv   = threadIdx.x >> 6;       // wave id 0..1 (uniform per wave)
    const int lane = threadIdx.x & 63;
    const int t4   = threadIdx.x * 4;        // consume offset (floats)

    // per-lane global pointers: each wave loads its 1KB half of each 2KB stream
    const float* og = outputs + base + wv * 256 + lane * 4;
    const float* lg = labels  + base + wv * 256 + lane * 4;

    float y0[4], vmax[4], vout[4];
    float obj = 0.f, szs = 0.f, offs = 0.f, cls = 0.f;
    float tp = 0.f, fp = 0.f, fn = 0.f;
#pragma unroll
    for (int i = 0; i < 4; ++i) { vmax[i] = -1.0f; vout[i] = 0.0f; }

    // stage group g (channels g*GR .. g*GR+4): 10 async 1KB loads per wave
    auto stage = [&](int g) {
#pragma unroll
        for (int ci = 0; ci < GR; ++ci) {
            const size_t choff = (size_t)(g * GR + ci) * HW;
            __builtin_amdgcn_global_load_lds((gp_t)(og + choff),
                                             (lp_t)&lds[2 * ci + 0][wv * 256], 16, 0, 0);
            __builtin_amdgcn_global_load_lds((gp_t)(lg + choff),
                                             (lp_t)&lds[2 * ci + 1][wv * 256], 16, 0, 0);
        }
    };

#pragma unroll
    for (int g = 0; g < NGRP; ++g) {
        stage(g);
        __syncthreads();                      // drains vmcnt(0): group g landed

        if (g == 0) {
            // ---- channels 0..4: BCE + F1 + size/offset L1
            F4 x, y;
            x.v = *(const float4*)&lds[0][t4];
            y.v = *(const float4*)&lds[1][t4];
#pragma unroll
            for (int i = 0; i < 4; ++i) {
                float xv = x.a[i], yv = y.a[i];
                float xc = fminf(fmaxf(xv,        EPSF), 1.0f - EPSF);
                float x1 = fminf(fmaxf(1.0f - xv, EPSF), 1.0f - EPSF);
                obj += -yv * (1.0f - xc) * __logf(xc)
                       - (1.0f - yv) * (1.0f - x1) * __logf(x1);
                float p  = (xv > 0.5f) ? 1.f : 0.f;
                float yt = (yv > 0.5f) ? 1.f : 0.f;
                tp += p * yt;
                fp += p * (1.f - yt);
                fn += (1.f - p) * yt;
                y0[i] = yv;
            }
#pragma unroll
            for (int ci = 1; ci <= 4; ++ci) {
                F4 o, l;
                o.v = *(const float4*)&lds[2 * ci + 0][t4];
                l.v = *(const float4*)&lds[2 * ci + 1][t4];
                float s = 0.f;
#pragma unroll
                for (int i = 0; i < 4; ++i) s += y0[i] * fabsf(o.a[i] - l.a[i]);
                if (ci <= 2) szs += s; else offs += s;
            }
        } else {
            // ---- channels 5..24: argmax(labels) carrying outputs
            // ascending channel order + strict > = argmax first-index tie-break
#pragma unroll
            for (int ci = 0; ci < GR; ++ci) {
                F4 o, l;
                o.v = *(const float4*)&lds[2 * ci + 0][t4];
                l.v = *(const float4*)&lds[2 * ci + 1][t4];
#pragma unroll
                for (int i = 0; i < 4; ++i) {
                    if (l.a[i] > vmax[i]) { vmax[i] = l.a[i]; vout[i] = o.a[i]; }
                }
            }
        }
        __syncthreads();                      // buffer reusable for next group
    }

#pragma unroll
    for (int i = 0; i < 4; ++i) cls += y0[i] * (-vout[i]);

    // ---- block reduction: 7 values (scratch aliased into lds -- all
    //      consumes are behind the final __syncthreads above)
    obj  = wave_reduce(obj);
    szs  = wave_reduce(szs);
    offs = wave_reduce(offs);
    cls  = wave_reduce(cls);
    tp   = wave_reduce(tp);
    fp   = wave_reduce(fp);
    fn   = wave_reduce(fn);

    float (*sm)[7]    = (float (*)[7])&lds[0][0];    // 2x7 floats
    float* fin        = &lds[0][64];                 // 52 floats
    unsigned* oldt_p  = (unsigned*)&lds[0][32];

    if (lane == 0) {
        sm[wv][0] = obj;  sm[wv][1] = szs; sm[wv][2] = offs;
        sm[wv][3] = cls;  sm[wv][4] = tp;  sm[wv][5] = fp;  sm[wv][6] = fn;
    }
    __syncthreads();
    if (threadIdx.x < 7) {
        float s = sm[0][threadIdx.x] + sm[1][threadIdx.x];
        if (threadIdx.x < 4) atomicAdd(&acc[threadIdx.x], s);
        else                 atomicAdd(&acc[4 + 3 * b + (threadIdx.x - 4)], s);
    }
    __syncthreads();          // all 7 atomics issued+drained

    // ---- ticket: last block finalizes (replaces yolo_fin launch)
    if (threadIdx.x == 0) {
        __threadfence();      // release our acc adds before the ticket
        *oldt_p = atomicAdd(ticket, 1u);
    }
    __syncthreads();
    if (*oldt_p == NBLK - 1) {
        if (threadIdx.x < 4 + 3 * NB) {
            // coherent RMW-read: sees every block's released adds
            fin[threadIdx.x] = atomicAdd(&acc[threadIdx.x], 0.0f);
        }
        __syncthreads();
        if (threadIdx.x == 0) {
            float objT = fin[0];
            float szT  = 0.1f * fin[1];
            float offT = 0.1f * fin[2];
            float clsT = fin[3];
            float f1 = 0.f;
            for (int bb = 0; bb < NB; ++bb) {
                float tpv = fin[4 + 3 * bb], fpv = fin[5 + 3 * bb], fnv = fin[6 + 3 * bb];
                float den = 2.f * tpv + fpv + fnv;
                f1 += (den > 0.f) ? (2.f * tpv) / fmaxf(den, 1.f) : 0.f;
            }
            f1 *= (1.0f / NB);
            out[0] = objT + szT + offT + clsT;
            out[1] = f1;
            out[2] = objT;
            out[3] = szT;
            out[4] = offT;
            out[5] = clsT;
        }
    }
}

extern "C" void kernel_launch(void* const* d_in, const int* in_sizes, int n_in,
                              void* d_out, int out_size, void* d_ws, size_t ws_size,
                              hipStream_t stream) {
    const float* outputs = (const float*)d_in[0];
    const float* labels  = (const float*)d_in[1];
    float* acc = (float*)d_ws;                    // [0..3] losses, [4+3b..] tp,fp,fn
    unsigned* ticket = (unsigned*)((float*)d_ws + 4 + 3 * NB);

    hipMemsetAsync(d_ws, 0, (4 + 3 * NB + 1) * sizeof(float), stream);
    yolo_main<<<NBLK, TPB, 0, stream>>>(outputs, labels, acc, ticket, (float*)d_out);
}